// Round 12
// baseline (289.452 us; speedup 1.0000x reference)
//
#include <hip/hip_runtime.h>

#define BATCH 16
#define NQ 2048
#define NK 2048

typedef short s16x8 __attribute__((ext_vector_type(8)));
typedef __bf16 bf16x8 __attribute__((ext_vector_type(8)));
typedef float f32x16 __attribute__((ext_vector_type(16)));
typedef float f32x4 __attribute__((ext_vector_type(4)));
typedef int i32x4 __attribute__((ext_vector_type(4)));
typedef unsigned u32x2 __attribute__((ext_vector_type(2)));

static __device__ __forceinline__ unsigned short f2bf(float f) {
  unsigned u = __builtin_bit_cast(unsigned, f);
  u += 0x7FFFu + ((u >> 16) & 1u);   // round-to-nearest-even
  return (unsigned short)(u >> 16);
}

static __device__ __forceinline__ f32x16 mfma32(s16x8 a, s16x8 b, f32x16 c) {
  return __builtin_amdgcn_mfma_f32_32x32x16_bf16(
      __builtin_bit_cast(bf16x8, a), __builtin_bit_cast(bf16x8, b), c, 0, 0, 0);
}

static __device__ __forceinline__ f32x4 mfma16(s16x8 a, s16x8 b, f32x4 c) {
  return __builtin_amdgcn_mfma_f32_16x16x32_bf16(
      __builtin_bit_cast(bf16x8, a), __builtin_bit_cast(bf16x8, b), c, 0, 0, 0);
}

// p = exp(10*tanh(s) - 10) = exp2(-28.8539.../(e^(2s)+1)), e^(2s)=exp2(2.88539*s)
static __device__ __forceinline__ float score_p(float s) {
  float u = __builtin_amdgcn_exp2f(s * 2.885390081777927f);
  return __builtin_amdgcn_exp2f(-28.853900817779268f * __builtin_amdgcn_rcpf(u + 1.0f));
}

// WT[n][k] = W[k][n] * scale, cast to bf16.  Grid: (256, 2) x 256 thr.
__global__ void prep_wt(const float* __restrict__ Wk, unsigned short* __restrict__ WkT,
                        const float* __restrict__ Wq, unsigned short* __restrict__ WqT) {
  const float* W = blockIdx.y ? Wq : Wk;
  unsigned short* WT = blockIdx.y ? WqT : WkT;
  float scale = blockIdx.y ? 0.0625f : 1.0f;   // fold 1/sqrt(256) into Wq
  int idx = blockIdx.x * 256 + threadIdx.x;
  int n = idx >> 8, k = idx & 255;
  WT[n * 256 + k] = f2bf(W[k * 256 + n] * scale);
}

// Projection; output packed in 16x16x32-MFMA fragment order for 16-row tiles:
//   Yf[((t16*8 + kk)*64 + lane)*8 + j] = Y[row = t16*16 + (lane&15)]
//                                         [e  = kk*32 + (lane>>4)*8 + j]
__global__ __launch_bounds__(256, 2) void proj_kernel(
    const float* __restrict__ Xk, const unsigned short* __restrict__ WkT,
    unsigned short* __restrict__ Yk,
    const float* __restrict__ Xq, const unsigned short* __restrict__ WqT,
    unsigned short* __restrict__ Yq) {
  const float* X;
  const unsigned short* WT;
  unsigned short* Y;
  if (blockIdx.y == 0) { X = Xk; WT = WkT; Y = Yk; }
  else                 { X = Xq; WT = WqT; Y = Yq; }

  int tid = threadIdx.x;
  int wave = tid >> 6, lane = tid & 63;
  int l31 = lane & 31, kh = lane >> 5;
  int r0 = blockIdx.x * 128 + wave * 32;

  const float* xp = X + (size_t)(r0 + l31) * 256 + kh * 8;

  f32x16 acc[8];
#pragma unroll
  for (int ct = 0; ct < 8; ++ct)
#pragma unroll
    for (int i = 0; i < 16; ++i) acc[ct][i] = 0.0f;

#pragma unroll
  for (int kk = 0; kk < 16; ++kk) {
    f32x4 a0 = *(const f32x4*)(xp + kk * 16);
    f32x4 a1 = *(const f32x4*)(xp + kk * 16 + 4);
    s16x8 af;
#pragma unroll
    for (int j = 0; j < 4; ++j) {
      af[j]     = (short)f2bf(a0[j]);
      af[4 + j] = (short)f2bf(a1[j]);
    }
#pragma unroll
    for (int ct = 0; ct < 8; ++ct) {
      s16x8 bw = *(const s16x8*)(WT + (size_t)(ct * 32 + l31) * 256 + kk * 16 + kh * 8);
      acc[ct] = mfma32(af, bw, acc[ct]);
    }
  }

  // epilogue: scatter into 16-row-tile fragment order
  int kg2 = l31 >> 3, j = l31 & 7;
#pragma unroll
  for (int ct = 0; ct < 8; ++ct) {
#pragma unroll
    for (int r = 0; r < 16; ++r) {
      int rrow = (r & 3) + 8 * (r >> 2) + 4 * kh;
      int row = r0 + rrow;
      Y[((size_t)((row >> 4) * 8 + ct) * 64 + kg2 * 16 + (row & 15)) * 8 + j] =
          f2bf(acc[ct][r]);
    }
  }
}

// Fused adjacency-pack + scores + tanh-clip + mask + softmax, one-pass.
// Grid: (128, 16) = 2048 blocks of 16 q-rows; 512 threads (8 waves), wave w
// owns cols [w*256, w*256+256) as 16 col-tiles of 16 (mfma 16x16x32).
// P-stash SPLIT: cts 0..7 in registers (16 u32), cts 8..15 in LDS (32 KB).
//   -> LDS/block ~38 KB (3 blocks need <=53 KB OK) and VGPR ~70 (3 blocks
//      need <=85 OK): targets 3 blocks/CU, occupancy ~75%.
//   (R10: all-LDS 71 KB -> 2 blocks, 203 us. R11: all-reg -> AGPR bloat,
//    1 block, 223 us. This is the midpoint.)
// Adjacency: nontemporal int4 loads + nibble/shfl-OR pack; NT output stores.
// XCD-aware remap: xcd = lin&7 owns batches {2*xcd, 2*xcd+1}.
__global__ __launch_bounds__(512, 2) void attn_kernel(
    const unsigned short* __restrict__ Kf, const unsigned short* __restrict__ Qf,
    const int* __restrict__ adj, float* __restrict__ out) {
  int lin = blockIdx.y * 128 + blockIdx.x;
  int b  = (lin & 7) * 2 + ((lin >> 3) & 1);
  int qt = lin >> 4;                 // 0..127: 16-row tile within batch
  int q0 = qt * 16;
  int tid = threadIdx.x;
  int wave = tid >> 6, lane = tid & 63;
  int l15 = lane & 15, kg = lane >> 4;
  int colbase = wave * 256;

  __shared__ unsigned plds[8 * 8 * 64 * 2];  // 32 KB: P bf16, cts 8..15
  __shared__ unsigned lmask[8 * 144];        // mask words, row stride 9 (pad)
  __shared__ float wsum[8][16];
  __shared__ float rrecip[16];

  // ---- wave-local adjacency pack (issue the HBM loads first) ----
  const i32x4* ap4 =
      (const i32x4*)(adj + ((size_t)b * NQ + q0) * (size_t)NK + colbase) + lane;
  unsigned* lm = lmask + wave * 144;
#pragma unroll
  for (int half = 0; half < 2; ++half) {
    i32x4 av[8];
#pragma unroll
    for (int r8 = 0; r8 < 8; ++r8)
      av[r8] = __builtin_nontemporal_load(ap4 + (size_t)(half * 8 + r8) * (NK / 4));
#pragma unroll
    for (int r8 = 0; r8 < 8; ++r8) {
      i32x4 v = av[r8];
      unsigned nib = (v[0] != 0 ? 1u : 0u) | (v[1] != 0 ? 2u : 0u) |
                     (v[2] != 0 ? 4u : 0u) | (v[3] != 0 ? 8u : 0u);
      unsigned m = nib << ((lane & 7) * 4);
      m |= __shfl_xor(m, 1);
      m |= __shfl_xor(m, 2);
      m |= __shfl_xor(m, 4);   // all 8 lanes of group g=lane>>3 now hold word g
      if ((lane & 7) == 0) lm[(half * 8 + r8) * 9 + (lane >> 3)] = m;
    }
  }

  // Q fragments: global tile = b*128 + qt (8 KB, coalesced 1 KB loads)
  const unsigned short* qp = Qf + (size_t)(b * 128 + qt) * 8 * 512;
  s16x8 aq[8];
#pragma unroll
  for (int kk = 0; kk < 8; ++kk)
    aq[kk] = *(const s16x8*)(qp + ((size_t)kk * 64 + lane) * 8);

  // no barrier: lmask/plds slices are wave-local (lgkmcnt orders same-wave LDS)

  const unsigned short* kfb = Kf + (size_t)b * 128 * 8 * 512;
  unsigned* pl = plds + (wave * 8) * 128 + lane * 2;

  float rsum[4] = {0.0f, 0.0f, 0.0f, 0.0f};
  unsigned prl[8], prh[8];   // P bf16x2 stash for cts 0..7 (static indexing)

#pragma unroll
  for (int ct = 0; ct < 16; ++ct) {
    f32x4 acc = {0.0f, 0.0f, 0.0f, 0.0f};
    const unsigned short* kpt = kfb + (size_t)(wave * 16 + ct) * 8 * 512;
#pragma unroll
    for (int kk = 0; kk < 8; ++kk) {
      s16x8 bk = *(const s16x8*)(kpt + ((size_t)kk * 64 + lane) * 8);
      acc = mfma16(aq[kk], bk, acc);
    }
    // D[row=kg*4+r][col=l15]; global col = colbase + ct*16 + l15
    unsigned shift = (unsigned)((ct & 1) * 16 + l15);
    float p[4];
#pragma unroll
    for (int r = 0; r < 4; ++r) {
      unsigned mw = lm[(kg * 4 + r) * 9 + (ct >> 1)];
      float e = score_p(acc[r]);
      p[r] = ((mw >> shift) & 1u) ? e : 0.0f;
      rsum[r] += p[r];
    }
    unsigned lo = (unsigned)f2bf(p[0]) | ((unsigned)f2bf(p[1]) << 16);
    unsigned hi = (unsigned)f2bf(p[2]) | ((unsigned)f2bf(p[3]) << 16);
    if (ct < 8) {
      prl[ct] = lo;          // compile-time index: stays in VGPRs
      prh[ct] = hi;
    } else {
      u32x2 v; v[0] = lo; v[1] = hi;
      *(u32x2*)(pl + (ct - 8) * 128) = v;
    }
  }

  // col-reduce within each 16-lane quarter (rows disjoint across quarters)
#pragma unroll
  for (int r = 0; r < 4; ++r) {
    float v = rsum[r];
    v += __shfl_xor(v, 1);
    v += __shfl_xor(v, 2);
    v += __shfl_xor(v, 4);
    v += __shfl_xor(v, 8);
    rsum[r] = v;
  }
  if (l15 == 0) {
#pragma unroll
    for (int r = 0; r < 4; ++r) wsum[wave][kg * 4 + r] = rsum[r];
  }
  __syncthreads();
  if (tid < 16) {
    float s = 0.0f;
#pragma unroll
    for (int w = 0; w < 8; ++w) s += wsum[w][tid];
    rrecip[tid] = 1.0f / s;
  }
  __syncthreads();

  float rc[4];
#pragma unroll
  for (int r = 0; r < 4; ++r) rc[r] = rrecip[kg * 4 + r];

  float* op = out + ((size_t)b * NQ + q0 + kg * 4) * (size_t)NK + colbase + l15;
  // cts 0..7 from registers
#pragma unroll
  for (int ct = 0; ct < 8; ++ct) {
    float p0 = __builtin_bit_cast(float, prl[ct] << 16);
    float p1 = __builtin_bit_cast(float, prl[ct] & 0xffff0000u);
    float p2 = __builtin_bit_cast(float, prh[ct] << 16);
    float p3 = __builtin_bit_cast(float, prh[ct] & 0xffff0000u);
    __builtin_nontemporal_store(p0 * rc[0], op + (size_t)0 * NK + ct * 16);
    __builtin_nontemporal_store(p1 * rc[1], op + (size_t)1 * NK + ct * 16);
    __builtin_nontemporal_store(p2 * rc[2], op + (size_t)2 * NK + ct * 16);
    __builtin_nontemporal_store(p3 * rc[3], op + (size_t)3 * NK + ct * 16);
  }
  // cts 8..15 from LDS
#pragma unroll
  for (int ct = 8; ct < 16; ++ct) {
    u32x2 v = *(const u32x2*)(pl + (ct - 8) * 128);
    float p0 = __builtin_bit_cast(float, v[0] << 16);
    float p1 = __builtin_bit_cast(float, v[0] & 0xffff0000u);
    float p2 = __builtin_bit_cast(float, v[1] << 16);
    float p3 = __builtin_bit_cast(float, v[1] & 0xffff0000u);
    __builtin_nontemporal_store(p0 * rc[0], op + (size_t)0 * NK + ct * 16);
    __builtin_nontemporal_store(p1 * rc[1], op + (size_t)1 * NK + ct * 16);
    __builtin_nontemporal_store(p2 * rc[2], op + (size_t)2 * NK + ct * 16);
    __builtin_nontemporal_store(p3 * rc[3], op + (size_t)3 * NK + ct * 16);
  }
}

extern "C" void kernel_launch(void* const* d_in, const int* in_sizes, int n_in,
                              void* d_out, int out_size, void* d_ws, size_t ws_size,
                              hipStream_t stream) {
  const float* k_in = (const float*)d_in[0];
  const float* q_in = (const float*)d_in[1];
  const int* adj    = (const int*)d_in[2];
  const float* Wk   = (const float*)d_in[3];
  const float* Wq   = (const float*)d_in[4];
  float* out = (float*)d_out;

  char* ws = (char*)d_ws;
  unsigned short* WkT = (unsigned short*)(ws);                           // 128 KB
  unsigned short* WqT = (unsigned short*)(ws + (1u << 17));              // 128 KB
  unsigned short* Kf  = (unsigned short*)(ws + (1u << 18));              // 16 MB
  unsigned short* Qf  = (unsigned short*)(ws + (1u << 18) + (1u << 24)); // 16 MB

  prep_wt<<<dim3(256, 2), 256, 0, stream>>>(Wk, WkT, Wq, WqT);

  proj_kernel<<<dim3(256, 2), 256, 0, stream>>>(k_in, WkT, Kf, q_in, WqT, Qf);

  attn_kernel<<<dim3(128, 16), 512, 0, stream>>>(Kf, Qf, adj, out);
}

// Round 13
// 271.708 us; speedup vs baseline: 1.0653x; 1.0653x over previous
//
#include <hip/hip_runtime.h>

#define BATCH 16
#define NQ 2048
#define NK 2048

typedef short s16x8 __attribute__((ext_vector_type(8)));
typedef __bf16 bf16x8 __attribute__((ext_vector_type(8)));
typedef float f32x16 __attribute__((ext_vector_type(16)));
typedef float f32x4 __attribute__((ext_vector_type(4)));
typedef int i32x4 __attribute__((ext_vector_type(4)));

static __device__ __forceinline__ unsigned short f2bf(float f) {
  unsigned u = __builtin_bit_cast(unsigned, f);
  u += 0x7FFFu + ((u >> 16) & 1u);   // round-to-nearest-even
  return (unsigned short)(u >> 16);
}

static __device__ __forceinline__ f32x16 mfma32(s16x8 a, s16x8 b, f32x16 c) {
  return __builtin_amdgcn_mfma_f32_32x32x16_bf16(
      __builtin_bit_cast(bf16x8, a), __builtin_bit_cast(bf16x8, b), c, 0, 0, 0);
}

static __device__ __forceinline__ f32x4 mfma16(s16x8 a, s16x8 b, f32x4 c) {
  return __builtin_amdgcn_mfma_f32_16x16x32_bf16(
      __builtin_bit_cast(bf16x8, a), __builtin_bit_cast(bf16x8, b), c, 0, 0, 0);
}

// p = exp(10*tanh(s) - 10) = exp2(-28.8539.../(e^(2s)+1)), e^(2s)=exp2(2.88539*s)
static __device__ __forceinline__ float score_p(float s) {
  float u = __builtin_amdgcn_exp2f(s * 2.885390081777927f);
  return __builtin_amdgcn_exp2f(-28.853900817779268f * __builtin_amdgcn_rcpf(u + 1.0f));
}

// WT[n][k] = W[k][n] * scale, cast to bf16.  Grid: (256, 2) x 256 thr.
__global__ void prep_wt(const float* __restrict__ Wk, unsigned short* __restrict__ WkT,
                        const float* __restrict__ Wq, unsigned short* __restrict__ WqT) {
  const float* W = blockIdx.y ? Wq : Wk;
  unsigned short* WT = blockIdx.y ? WqT : WkT;
  float scale = blockIdx.y ? 0.0625f : 1.0f;   // fold 1/sqrt(256) into Wq
  int idx = blockIdx.x * 256 + threadIdx.x;
  int n = idx >> 8, k = idx & 255;
  WT[n * 256 + k] = f2bf(W[k * 256 + n] * scale);
}

// Projection; output packed in 16x16x32-MFMA fragment order for 16-row tiles:
//   Yf[((t16*8 + kk)*64 + lane)*8 + j] = Y[row = t16*16 + (lane&15)]
//                                         [e  = kk*32 + (lane>>4)*8 + j]
__global__ __launch_bounds__(256, 2) void proj_kernel(
    const float* __restrict__ Xk, const unsigned short* __restrict__ WkT,
    unsigned short* __restrict__ Yk,
    const float* __restrict__ Xq, const unsigned short* __restrict__ WqT,
    unsigned short* __restrict__ Yq) {
  const float* X;
  const unsigned short* WT;
  unsigned short* Y;
  if (blockIdx.y == 0) { X = Xk; WT = WkT; Y = Yk; }
  else                 { X = Xq; WT = WqT; Y = Yq; }

  int tid = threadIdx.x;
  int wave = tid >> 6, lane = tid & 63;
  int l31 = lane & 31, kh = lane >> 5;
  int r0 = blockIdx.x * 128 + wave * 32;

  const float* xp = X + (size_t)(r0 + l31) * 256 + kh * 8;

  f32x16 acc[8];
#pragma unroll
  for (int ct = 0; ct < 8; ++ct)
#pragma unroll
    for (int i = 0; i < 16; ++i) acc[ct][i] = 0.0f;

#pragma unroll
  for (int kk = 0; kk < 16; ++kk) {
    f32x4 a0 = *(const f32x4*)(xp + kk * 16);
    f32x4 a1 = *(const f32x4*)(xp + kk * 16 + 4);
    s16x8 af;
#pragma unroll
    for (int j = 0; j < 4; ++j) {
      af[j]     = (short)f2bf(a0[j]);
      af[4 + j] = (short)f2bf(a1[j]);
    }
#pragma unroll
    for (int ct = 0; ct < 8; ++ct) {
      s16x8 bw = *(const s16x8*)(WT + (size_t)(ct * 32 + l31) * 256 + kk * 16 + kh * 8);
      acc[ct] = mfma32(af, bw, acc[ct]);
    }
  }

  // epilogue: scatter into 16-row-tile fragment order
  int kg2 = l31 >> 3, j = l31 & 7;
#pragma unroll
  for (int ct = 0; ct < 8; ++ct) {
#pragma unroll
    for (int r = 0; r < 16; ++r) {
      int rrow = (r & 3) + 8 * (r >> 2) + 4 * kh;
      int row = r0 + rrow;
      Y[((size_t)((row >> 4) * 8 + ct) * 64 + kg2 * 16 + (row & 15)) * 8 + j] =
          f2bf(acc[ct][r]);
    }
  }
}

// Fused adjacency-pack + scores + tanh-clip + mask + softmax.
// TWO-PASS, NO P-STASH (register stashes provably bloat AGPRs -> 1 block/CU;
// LDS stash caps at 2 blocks/CU; recompute is nearly free at 7% MfmaUtil).
// Grid: (128, 16) = 2048 blocks of 16 q-rows; 512 threads (8 waves), wave w
// owns cols [w*256, w*256+256) as 16 col-tiles of 16 (mfma 16x16x32).
// Register budget: aq 32 + adjacency transients 16 (4-row chunks) + addr ~15
// + rsum 4 -> ~80 VGPR, acc 4 AGPR, LDS ~6 KB -> ~3 blocks/CU by VGPR only.
// Pass 1: scores -> row sums.  Pass 2: recompute, normalize, NT-store.
// K panels stay L2-resident (2 MB/XCD via XCD-aware batch remap), so the
// second K sweep costs L2 BW, not HBM.
__global__ __launch_bounds__(512, 2) void attn_kernel(
    const unsigned short* __restrict__ Kf, const unsigned short* __restrict__ Qf,
    const int* __restrict__ adj, float* __restrict__ out) {
  int lin = blockIdx.y * 128 + blockIdx.x;
  int b  = (lin & 7) * 2 + ((lin >> 3) & 1);
  int qt = lin >> 4;                 // 0..127: 16-row tile within batch
  int q0 = qt * 16;
  int tid = threadIdx.x;
  int wave = tid >> 6, lane = tid & 63;
  int l15 = lane & 15, kg = lane >> 4;
  int colbase = wave * 256;

  __shared__ unsigned lmask[8 * 144];   // mask words, row stride 9 (pad)
  __shared__ float wsum[8][16];
  __shared__ float rrecip[16];

  // ---- wave-local adjacency pack, 4-row chunks (16 transient VGPRs) ----
  const i32x4* ap4 =
      (const i32x4*)(adj + ((size_t)b * NQ + q0) * (size_t)NK + colbase) + lane;
  unsigned* lm = lmask + wave * 144;
#pragma unroll
  for (int quad = 0; quad < 4; ++quad) {
    i32x4 av[4];
#pragma unroll
    for (int r4 = 0; r4 < 4; ++r4)
      av[r4] = __builtin_nontemporal_load(ap4 + (size_t)(quad * 4 + r4) * (NK / 4));
#pragma unroll
    for (int r4 = 0; r4 < 4; ++r4) {
      i32x4 v = av[r4];
      unsigned nib = (v[0] != 0 ? 1u : 0u) | (v[1] != 0 ? 2u : 0u) |
                     (v[2] != 0 ? 4u : 0u) | (v[3] != 0 ? 8u : 0u);
      unsigned m = nib << ((lane & 7) * 4);
      m |= __shfl_xor(m, 1);
      m |= __shfl_xor(m, 2);
      m |= __shfl_xor(m, 4);   // all 8 lanes of group g=lane>>3 now hold word g
      if ((lane & 7) == 0) lm[(quad * 4 + r4) * 9 + (lane >> 3)] = m;
    }
  }

  // Q fragments: global tile = b*128 + qt (8 KB, coalesced 1 KB loads)
  const unsigned short* qp = Qf + (size_t)(b * 128 + qt) * 8 * 512;
  s16x8 aq[8];
#pragma unroll
  for (int kk = 0; kk < 8; ++kk)
    aq[kk] = __builtin_nontemporal_load((const s16x8*)(qp + ((size_t)kk * 64 + lane) * 8));

  // no barrier: lmask slice is wave-local (lgkmcnt orders same-wave LDS)

  const unsigned short* kfb = Kf + (size_t)b * 128 * 8 * 512;

  // ---- PASS 1: scores -> row sums ----
  float rsum[4] = {0.0f, 0.0f, 0.0f, 0.0f};
#pragma unroll 4
  for (int ct = 0; ct < 16; ++ct) {
    f32x4 acc = {0.0f, 0.0f, 0.0f, 0.0f};
    const unsigned short* kpt = kfb + (size_t)(wave * 16 + ct) * 8 * 512;
#pragma unroll
    for (int kk = 0; kk < 8; ++kk) {
      s16x8 bk = *(const s16x8*)(kpt + ((size_t)kk * 64 + lane) * 8);
      acc = mfma16(aq[kk], bk, acc);
    }
    unsigned shift = (unsigned)((ct & 1) * 16 + l15);
#pragma unroll
    for (int r = 0; r < 4; ++r) {
      unsigned mw = lm[(kg * 4 + r) * 9 + (ct >> 1)];
      float e = score_p(acc[r]);
      rsum[r] += ((mw >> shift) & 1u) ? e : 0.0f;
    }
  }

  // col-reduce within each 16-lane quarter (rows disjoint across quarters)
#pragma unroll
  for (int r = 0; r < 4; ++r) {
    float v = rsum[r];
    v += __shfl_xor(v, 1);
    v += __shfl_xor(v, 2);
    v += __shfl_xor(v, 4);
    v += __shfl_xor(v, 8);
    rsum[r] = v;
  }
  if (l15 == 0) {
#pragma unroll
    for (int r = 0; r < 4; ++r) wsum[wave][kg * 4 + r] = rsum[r];
  }
  __syncthreads();
  if (tid < 16) {
    float s = 0.0f;
#pragma unroll
    for (int w = 0; w < 8; ++w) s += wsum[w][tid];
    rrecip[tid] = 1.0f / s;
  }
  __syncthreads();

  float rc[4];
#pragma unroll
  for (int r = 0; r < 4; ++r) rc[r] = rrecip[kg * 4 + r];

  // ---- PASS 2: recompute scores, normalize, NT-store ----
  float* op = out + ((size_t)b * NQ + q0 + kg * 4) * (size_t)NK + colbase + l15;
#pragma unroll 4
  for (int ct = 0; ct < 16; ++ct) {
    f32x4 acc = {0.0f, 0.0f, 0.0f, 0.0f};
    const unsigned short* kpt = kfb + (size_t)(wave * 16 + ct) * 8 * 512;
#pragma unroll
    for (int kk = 0; kk < 8; ++kk) {
      s16x8 bk = *(const s16x8*)(kpt + ((size_t)kk * 64 + lane) * 8);
      acc = mfma16(aq[kk], bk, acc);
    }
    unsigned shift = (unsigned)((ct & 1) * 16 + l15);
#pragma unroll
    for (int r = 0; r < 4; ++r) {
      unsigned mw = lm[(kg * 4 + r) * 9 + (ct >> 1)];
      float e = score_p(acc[r]);
      float p = ((mw >> shift) & 1u) ? e : 0.0f;
      __builtin_nontemporal_store(p * rc[r], op + (size_t)r * NK + ct * 16);
    }
  }
}

extern "C" void kernel_launch(void* const* d_in, const int* in_sizes, int n_in,
                              void* d_out, int out_size, void* d_ws, size_t ws_size,
                              hipStream_t stream) {
  const float* k_in = (const float*)d_in[0];
  const float* q_in = (const float*)d_in[1];
  const int* adj    = (const int*)d_in[2];
  const float* Wk   = (const float*)d_in[3];
  const float* Wq   = (const float*)d_in[4];
  float* out = (float*)d_out;

  char* ws = (char*)d_ws;
  unsigned short* WkT = (unsigned short*)(ws);                           // 128 KB
  unsigned short* WqT = (unsigned short*)(ws + (1u << 17));              // 128 KB
  unsigned short* Kf  = (unsigned short*)(ws + (1u << 18));              // 16 MB
  unsigned short* Qf  = (unsigned short*)(ws + (1u << 18) + (1u << 24)); // 16 MB

  prep_wt<<<dim3(256, 2), 256, 0, stream>>>(Wk, WkT, Wq, WqT);

  proj_kernel<<<dim3(256, 2), 256, 0, stream>>>(k_in, WkT, Kf, q_in, WqT, Qf);

  attn_kernel<<<dim3(128, 16), 512, 0, stream>>>(Kf, Qf, adj, out);
}

// Round 14
// 256.570 us; speedup vs baseline: 1.1282x; 1.0590x over previous
//
#include <hip/hip_runtime.h>

#define BATCH 16
#define NQ 2048
#define NK 2048

typedef short s16x8 __attribute__((ext_vector_type(8)));
typedef __bf16 bf16x8 __attribute__((ext_vector_type(8)));
typedef float f32x16 __attribute__((ext_vector_type(16)));
typedef float f32x4 __attribute__((ext_vector_type(4)));
typedef int i32x4 __attribute__((ext_vector_type(4)));
typedef unsigned u32x2 __attribute__((ext_vector_type(2)));

static __device__ __forceinline__ unsigned short f2bf(float f) {
  unsigned u = __builtin_bit_cast(unsigned, f);
  u += 0x7FFFu + ((u >> 16) & 1u);   // round-to-nearest-even
  return (unsigned short)(u >> 16);
}

static __device__ __forceinline__ f32x16 mfma32(s16x8 a, s16x8 b, f32x16 c) {
  return __builtin_amdgcn_mfma_f32_32x32x16_bf16(
      __builtin_bit_cast(bf16x8, a), __builtin_bit_cast(bf16x8, b), c, 0, 0, 0);
}

static __device__ __forceinline__ f32x4 mfma16(s16x8 a, s16x8 b, f32x4 c) {
  return __builtin_amdgcn_mfma_f32_16x16x32_bf16(
      __builtin_bit_cast(bf16x8, a), __builtin_bit_cast(bf16x8, b), c, 0, 0, 0);
}

// p = exp(10*tanh(s) - 10) = exp2(-28.8539.../(e^(2s)+1)), e^(2s)=exp2(2.88539*s)
static __device__ __forceinline__ float score_p(float s) {
  float u = __builtin_amdgcn_exp2f(s * 2.885390081777927f);
  return __builtin_amdgcn_exp2f(-28.853900817779268f * __builtin_amdgcn_rcpf(u + 1.0f));
}

// WT[n][k] = W[k][n] * scale, cast to bf16.  Grid: (256, 2) x 256 thr.
__global__ void prep_wt(const float* __restrict__ Wk, unsigned short* __restrict__ WkT,
                        const float* __restrict__ Wq, unsigned short* __restrict__ WqT) {
  const float* W = blockIdx.y ? Wq : Wk;
  unsigned short* WT = blockIdx.y ? WqT : WkT;
  float scale = blockIdx.y ? 0.0625f : 1.0f;   // fold 1/sqrt(256) into Wq
  int idx = blockIdx.x * 256 + threadIdx.x;
  int n = idx >> 8, k = idx & 255;
  WT[n * 256 + k] = f2bf(W[k * 256 + n] * scale);
}

// Projection; output packed in 16x16x32-MFMA fragment order for 16-row tiles:
//   Yf[((t16*8 + kk)*64 + lane)*8 + j] = Y[row = t16*16 + (lane&15)]
//                                         [e  = kk*32 + (lane>>4)*8 + j]
__global__ __launch_bounds__(256, 2) void proj_kernel(
    const float* __restrict__ Xk, const unsigned short* __restrict__ WkT,
    unsigned short* __restrict__ Yk,
    const float* __restrict__ Xq, const unsigned short* __restrict__ WqT,
    unsigned short* __restrict__ Yq) {
  const float* X;
  const unsigned short* WT;
  unsigned short* Y;
  if (blockIdx.y == 0) { X = Xk; WT = WkT; Y = Yk; }
  else                 { X = Xq; WT = WqT; Y = Yq; }

  int tid = threadIdx.x;
  int wave = tid >> 6, lane = tid & 63;
  int l31 = lane & 31, kh = lane >> 5;
  int r0 = blockIdx.x * 128 + wave * 32;

  const float* xp = X + (size_t)(r0 + l31) * 256 + kh * 8;

  f32x16 acc[8];
#pragma unroll
  for (int ct = 0; ct < 8; ++ct)
#pragma unroll
    for (int i = 0; i < 16; ++i) acc[ct][i] = 0.0f;

#pragma unroll
  for (int kk = 0; kk < 16; ++kk) {
    f32x4 a0 = *(const f32x4*)(xp + kk * 16);
    f32x4 a1 = *(const f32x4*)(xp + kk * 16 + 4);
    s16x8 af;
#pragma unroll
    for (int j = 0; j < 4; ++j) {
      af[j]     = (short)f2bf(a0[j]);
      af[4 + j] = (short)f2bf(a1[j]);
    }
#pragma unroll
    for (int ct = 0; ct < 8; ++ct) {
      s16x8 bw = *(const s16x8*)(WT + (size_t)(ct * 32 + l31) * 256 + kk * 16 + kh * 8);
      acc[ct] = mfma32(af, bw, acc[ct]);
    }
  }

  // epilogue: scatter into 16-row-tile fragment order
  int kg2 = l31 >> 3, j = l31 & 7;
#pragma unroll
  for (int ct = 0; ct < 8; ++ct) {
#pragma unroll
    for (int r = 0; r < 16; ++r) {
      int rrow = (r & 3) + 8 * (r >> 2) + 4 * kh;
      int row = r0 + rrow;
      Y[((size_t)((row >> 4) * 8 + ct) * 64 + kg2 * 16 + (row & 15)) * 8 + j] =
          f2bf(acc[ct][r]);
    }
  }
}

// Fused adjacency-pack + scores + tanh-clip + mask + softmax, ONE-PASS,
// P stash in LDS (64 KB, wave-private slices; proven R10 layout = 203 us,
// 2 blocks/CU) + explicit K DOUBLE-BUFFER: bkA/bkB ping-pong issues the next
// col-tile's 8 K loads before the current tile's score phase, hiding the
// ~250-cyc L2 latency that R10 exposed per tile (VGPR_Count was 52 -> the
// compiler was NOT prefetching). Budget: aq 32 + bk 64 + misc ~25 + acc 4
// AGPR ~ 125 <= 128-reg cap at 16 waves/CU.
// Adjacency: NT int4 loads + nibble/shfl-OR pack (R13, FETCH -15%).
// Output: NT stores (don't evict K panels from L2).
// XCD-aware remap: xcd = lin&7 owns batches {2*xcd, 2*xcd+1} (2 MB K / L2).
__global__ __launch_bounds__(512, 2) void attn_kernel(
    const unsigned short* __restrict__ Kf, const unsigned short* __restrict__ Qf,
    const int* __restrict__ adj, float* __restrict__ out) {
  int lin = blockIdx.y * 128 + blockIdx.x;
  int b  = (lin & 7) * 2 + ((lin >> 3) & 1);
  int qt = lin >> 4;                 // 0..127: 16-row tile within batch
  int q0 = qt * 16;
  int tid = threadIdx.x;
  int wave = tid >> 6, lane = tid & 63;
  int l15 = lane & 15, kg = lane >> 4;
  int colbase = wave * 256;

  __shared__ unsigned plds[8 * 16 * 64 * 2];  // 64 KB: P bf16 [wave][ct][lane][2]
  __shared__ unsigned lmask[8 * 144];         // mask words, row stride 9 (pad)
  __shared__ float wsum[8][16];
  __shared__ float rrecip[16];

  // ---- wave-local adjacency pack, NT int4 loads, 4-row chunks ----
  const i32x4* ap4 =
      (const i32x4*)(adj + ((size_t)b * NQ + q0) * (size_t)NK + colbase) + lane;
  unsigned* lm = lmask + wave * 144;
#pragma unroll
  for (int quad = 0; quad < 4; ++quad) {
    i32x4 av[4];
#pragma unroll
    for (int r4 = 0; r4 < 4; ++r4)
      av[r4] = __builtin_nontemporal_load(ap4 + (size_t)(quad * 4 + r4) * (NK / 4));
#pragma unroll
    for (int r4 = 0; r4 < 4; ++r4) {
      i32x4 v = av[r4];
      unsigned nib = (v[0] != 0 ? 1u : 0u) | (v[1] != 0 ? 2u : 0u) |
                     (v[2] != 0 ? 4u : 0u) | (v[3] != 0 ? 8u : 0u);
      unsigned m = nib << ((lane & 7) * 4);
      m |= __shfl_xor(m, 1);
      m |= __shfl_xor(m, 2);
      m |= __shfl_xor(m, 4);   // all 8 lanes of group g=lane>>3 now hold word g
      if ((lane & 7) == 0) lm[(quad * 4 + r4) * 9 + (lane >> 3)] = m;
    }
  }

  // Q fragments: global tile = b*128 + qt (8 KB, coalesced 1 KB loads)
  const unsigned short* qp = Qf + (size_t)(b * 128 + qt) * 8 * 512;
  s16x8 aq[8];
#pragma unroll
  for (int kk = 0; kk < 8; ++kk)
    aq[kk] = __builtin_nontemporal_load(
        (const s16x8*)(qp + ((size_t)kk * 64 + lane) * 8));

  // no barrier: lmask/plds slices are wave-local (lgkmcnt orders same-wave LDS)

  const unsigned short* kfb = Kf + (size_t)b * 128 * 8 * 512;
  unsigned* pl = plds + (wave * 16) * 128 + lane * 2;

  float rsum[4] = {0.0f, 0.0f, 0.0f, 0.0f};
  s16x8 bkA[8], bkB[8];

#define KLOAD(CT, DST)                                                         \
  {                                                                            \
    const unsigned short* kpt = kfb + (size_t)(wave * 16 + (CT)) * 4096;       \
    _Pragma("unroll") for (int kk = 0; kk < 8; ++kk)                           \
        DST[kk] = *(const s16x8*)(kpt + ((size_t)kk * 64 + lane) * 8);         \
  }

#define PROCESS(CT, BK)                                                        \
  {                                                                            \
    f32x4 acc = {0.0f, 0.0f, 0.0f, 0.0f};                                      \
    _Pragma("unroll") for (int kk = 0; kk < 8; ++kk)                           \
        acc = mfma16(aq[kk], BK[kk], acc);                                     \
    unsigned shift = (unsigned)(((CT) & 1) * 16 + l15);                        \
    float p[4];                                                                \
    _Pragma("unroll") for (int r = 0; r < 4; ++r) {                            \
      unsigned mw = lm[(kg * 4 + r) * 9 + ((CT) >> 1)];                        \
      float e = score_p(acc[r]);                                               \
      p[r] = ((mw >> shift) & 1u) ? e : 0.0f;                                  \
      rsum[r] += p[r];                                                         \
    }                                                                          \
    u32x2 v;                                                                   \
    v[0] = (unsigned)f2bf(p[0]) | ((unsigned)f2bf(p[1]) << 16);                \
    v[1] = (unsigned)f2bf(p[2]) | ((unsigned)f2bf(p[3]) << 16);                \
    *(u32x2*)(pl + (CT)*128) = v;                                              \
  }

  KLOAD(0, bkA)
#pragma unroll
  for (int cp = 0; cp < 8; ++cp) {
    KLOAD(2 * cp + 1, bkB)      // prefetch odd tile before consuming even
    PROCESS(2 * cp, bkA)
    if (cp < 7) KLOAD(2 * cp + 2, bkA)   // prefetch next even before odd
    PROCESS(2 * cp + 1, bkB)
  }
#undef KLOAD
#undef PROCESS

  // col-reduce within each 16-lane quarter (rows disjoint across quarters)
#pragma unroll
  for (int r = 0; r < 4; ++r) {
    float v = rsum[r];
    v += __shfl_xor(v, 1);
    v += __shfl_xor(v, 2);
    v += __shfl_xor(v, 4);
    v += __shfl_xor(v, 8);
    rsum[r] = v;
  }
  if (l15 == 0) {
#pragma unroll
    for (int r = 0; r < 4; ++r) wsum[wave][kg * 4 + r] = rsum[r];
  }
  __syncthreads();
  if (tid < 16) {
    float s = 0.0f;
#pragma unroll
    for (int w = 0; w < 8; ++w) s += wsum[w][tid];
    rrecip[tid] = 1.0f / s;
  }
  __syncthreads();

  float rc[4];
#pragma unroll
  for (int r = 0; r < 4; ++r) rc[r] = rrecip[kg * 4 + r];

  // read P back from LDS, normalize, NT-store
  float* op = out + ((size_t)b * NQ + q0 + kg * 4) * (size_t)NK + colbase + l15;
#pragma unroll 4
  for (int ct = 0; ct < 16; ++ct) {
    u32x2 v = *(const u32x2*)(pl + ct * 128);
    float p0 = __builtin_bit_cast(float, v[0] << 16);
    float p1 = __builtin_bit_cast(float, v[0] & 0xffff0000u);
    float p2 = __builtin_bit_cast(float, v[1] << 16);
    float p3 = __builtin_bit_cast(float, v[1] & 0xffff0000u);
    __builtin_nontemporal_store(p0 * rc[0], op + (size_t)0 * NK + ct * 16);
    __builtin_nontemporal_store(p1 * rc[1], op + (size_t)1 * NK + ct * 16);
    __builtin_nontemporal_store(p2 * rc[2], op + (size_t)2 * NK + ct * 16);
    __builtin_nontemporal_store(p3 * rc[3], op + (size_t)3 * NK + ct * 16);
  }
}

extern "C" void kernel_launch(void* const* d_in, const int* in_sizes, int n_in,
                              void* d_out, int out_size, void* d_ws, size_t ws_size,
                              hipStream_t stream) {
  const float* k_in = (const float*)d_in[0];
  const float* q_in = (const float*)d_in[1];
  const int* adj    = (const int*)d_in[2];
  const float* Wk   = (const float*)d_in[3];
  const float* Wq   = (const float*)d_in[4];
  float* out = (float*)d_out;

  char* ws = (char*)d_ws;
  unsigned short* WkT = (unsigned short*)(ws);                           // 128 KB
  unsigned short* WqT = (unsigned short*)(ws + (1u << 17));              // 128 KB
  unsigned short* Kf  = (unsigned short*)(ws + (1u << 18));              // 16 MB
  unsigned short* Qf  = (unsigned short*)(ws + (1u << 18) + (1u << 24)); // 16 MB

  prep_wt<<<dim3(256, 2), 256, 0, stream>>>(Wk, WkT, Wq, WqT);

  proj_kernel<<<dim3(256, 2), 256, 0, stream>>>(k_in, WkT, Kf, q_in, WqT, Qf);

  attn_kernel<<<dim3(128, 16), 512, 0, stream>>>(Kf, Qf, adj, out);
}